// Round 3
// baseline (364.233 us; speedup 1.0000x reference)
//
#include <hip/hip_runtime.h>
#include <cstdint>
#include <cstddef>

// T=8192 tokens, E=64 experts, D=2048, capacity=2*ceil(T/E)=256
#define T_TOK 8192
#define NE    64
#define ND    2048
#define CAP   256

#define GEMM_B 128   // gemm blocks (64 tokens each)
#define ZB     4096  // zero blocks

// ---------------- kernel A: fused (GEMM 64tok x 64exp full-K + epilogue) + zero-fill
// blocks [0,GEMM_B): logits GEMM in exact fp32 + softmax/argmax epilogue
// blocks [GEMM_B, GEMM_B+ZB): grid-stride float4 zero of the whole output
__global__ __launch_bounds__(128) void kA(
    const float* __restrict__ x, const float* __restrict__ wg,
    const float* __restrict__ gum,
    int* __restrict__ idx1o, int* __restrict__ idx2o,
    float* __restrict__ g1o, float* __restrict__ g2o,
    float* __restrict__ meb,
    float4* __restrict__ o4, long n4, float* __restrict__ o, long n) {
  __shared__ float xs[64][68];   // [k][token'] (XOR-swizzled column)
  __shared__ float wt[64][68];   // [k][expert']
  __shared__ float mred[2][64];

  if (blockIdx.x >= GEMM_B) {
    long i = (long)(blockIdx.x - GEMM_B) * 128 + threadIdx.x;
    const long stride = (long)ZB * 128;
    const float4 z = make_float4(0.f, 0.f, 0.f, 0.f);
    for (; i < n4; i += stride) o4[i] = z;
    if (blockIdx.x == GEMM_B && threadIdx.x == 0) {
      for (long j = n4 * 4; j < n; ++j) o[j] = 0.f;  // odd tail element
    }
    return;
  }

  const int tid = threadIdx.x;
  const int t0 = blockIdx.x * 64;
  const int tg8 = (tid >> 4) << 3;  // token base within tile (8 tokens)
  const int eg4 = (tid & 15) << 2;  // expert base (4 experts)

  float acc[8][4];
#pragma unroll
  for (int i = 0; i < 8; ++i)
#pragma unroll
    for (int j = 0; j < 4; ++j) acc[i][j] = 0.f;

  for (int kt = 0; kt < ND; kt += 64) {
    // stage 64x64 tiles of x and wg, transposed to [k][row], swizzled stores
#pragma unroll
    for (int it = 0; it < 8; ++it) {
      const int j = tid + it * 128;      // 0..1023
      const int r = j >> 4;              // row (token or expert) 0..63
      const int cb = (j & 15) << 2;      // k-offset base
      const int sw = ((cb >> 2) & 7) << 2;
      const int rs = r ^ sw;
      float4 vx = *reinterpret_cast<const float4*>(x + (size_t)(t0 + r) * ND + kt + cb);
      xs[cb + 0][rs] = vx.x; xs[cb + 1][rs] = vx.y;
      xs[cb + 2][rs] = vx.z; xs[cb + 3][rs] = vx.w;
      float4 vw = *reinterpret_cast<const float4*>(wg + (size_t)r * ND + kt + cb);
      wt[cb + 0][rs] = vw.x; wt[cb + 1][rs] = vw.y;
      wt[cb + 2][rs] = vw.z; wt[cb + 3][rs] = vw.w;
    }
    __syncthreads();
#pragma unroll 4
    for (int k = 0; k < 64; ++k) {
      const int s = ((k >> 2) & 7) << 2;
      float4 a0 = *reinterpret_cast<const float4*>(&xs[k][tg8 ^ s]);
      float4 a1 = *reinterpret_cast<const float4*>(&xs[k][(tg8 + 4) ^ s]);
      float4 b  = *reinterpret_cast<const float4*>(&wt[k][eg4 ^ s]);
      float av[8] = {a0.x, a0.y, a0.z, a0.w, a1.x, a1.y, a1.z, a1.w};
      float bv[4] = {b.x, b.y, b.z, b.w};
#pragma unroll
      for (int i = 0; i < 8; ++i)
#pragma unroll
        for (int j = 0; j < 4; ++j) acc[i][j] = fmaf(av[i], bv[j], acc[i][j]);
    }
    __syncthreads();
  }

  // dump logits into xs storage (token-major, stride 68, no swizzle)
  float* lgp = &xs[0][0];
#pragma unroll
  for (int i = 0; i < 8; ++i) {
    float4 v = make_float4(acc[i][0], acc[i][1], acc[i][2], acc[i][3]);
    *reinterpret_cast<float4*>(lgp + (size_t)(tg8 + i) * 68 + eg4) = v;
  }
  __syncthreads();

  // epilogue: wave handles 32 tokens; lane = expert
  const int wave = tid >> 6;
  const int lane = tid & 63;
  float meacc = 0.f;
  for (int i = 0; i < 32; ++i) {
    const int tt = wave * 32 + i;
    const int t = t0 + tt;
    const float logit = lgp[tt * 68 + lane];
    // softmax across wave (lane = expert)
    float m = logit;
#pragma unroll
    for (int o2 = 32; o2; o2 >>= 1) m = fmaxf(m, __shfl_xor(m, o2));
    const float ex = expf(logit - m);
    float s = ex;
#pragma unroll
    for (int o2 = 32; o2; o2 >>= 1) s += __shfl_xor(s, o2);
    const float gate = ex / s;
    meacc += gate;
    // argmax over logits (first-index tie-break)
    float v1 = logit; int i1 = lane;
#pragma unroll
    for (int o2 = 32; o2; o2 >>= 1) {
      float vv = __shfl_xor(v1, o2); int jj = __shfl_xor(i1, o2);
      if (vv > v1 || (vv == v1 && jj < i1)) { v1 = vv; i1 = jj; }
    }
    // second expert: gumbel-noised logits, top-1 masked
    float v2 = (lane == i1) ? -__builtin_inff() : logit + gum[(size_t)t * NE + lane];
    int i2 = lane;
#pragma unroll
    for (int o2 = 32; o2; o2 >>= 1) {
      float vv = __shfl_xor(v2, o2); int jj = __shfl_xor(i2, o2);
      if (vv > v2 || (vv == v2 && jj < i2)) { v2 = vv; i2 = jj; }
    }
    const float gv1 = __shfl(gate, i1);
    const float gv2 = __shfl(gate, i2);
    if (lane == 0) {
      idx1o[t] = i1; idx2o[t] = i2; g1o[t] = gv1; g2o[t] = gv2;
    }
  }
  mred[wave][lane] = meacc;
  __syncthreads();
  if (tid < 64) meb[(size_t)blockIdx.x * NE + tid] = mred[0][tid] + mred[1][tid];
}

// ------------------------------------------------- per-expert token scan
__global__ __launch_bounds__(256) void k_scan(
    const int* __restrict__ idx1, const int* __restrict__ idx2,
    int* __restrict__ loc1, int* __restrict__ loc2, int* __restrict__ cnt1) {
  const int e = blockIdx.x;
  const int tid = threadIdx.x;
  const int base = tid * 32;
  int c1 = 0, c2 = 0;
  for (int i = 0; i < 32; ++i) {
    c1 += (idx1[base + i] == e);
    c2 += (idx2[base + i] == e);
  }
  const int lane = tid & 63, wave = tid >> 6;
  int s1 = c1, s2 = c2;
#pragma unroll
  for (int o = 1; o < 64; o <<= 1) {
    int t1 = __shfl_up(s1, o), t2 = __shfl_up(s2, o);
    if (lane >= o) { s1 += t1; s2 += t2; }
  }
  __shared__ int wt1[4], wt2[4];
  if (lane == 63) { wt1[wave] = s1; wt2[wave] = s2; }
  __syncthreads();
  int off1 = 0, off2 = 0, tot1 = 0;
#pragma unroll
  for (int w = 0; w < 4; ++w) {
    tot1 += wt1[w];
    if (w < wave) { off1 += wt1[w]; off2 += wt2[w]; }
  }
  int p1 = off1 + s1 - c1;          // exclusive prefix = token rank in expert
  int p2 = off2 + s2 - c2 + tot1;   // + sum(mask1[:,e]) per reference
  for (int i = 0; i < 32; ++i) {
    if (idx1[base + i] == e) loc1[base + i] = p1++;
    if (idx2[base + i] == e) loc2[base + i] = p2++;
  }
  if (tid == 0) cnt1[e] = tot1;
}

// ------------------------------------- scatter combine/dispatch + l_aux
__global__ __launch_bounds__(256) void k_scat(
    const int* __restrict__ idx1, const int* __restrict__ idx2,
    const float* __restrict__ g1, const float* __restrict__ g2,
    const int* __restrict__ loc1, const int* __restrict__ loc2,
    const float* __restrict__ meb, const int* __restrict__ cnt1,
    float* __restrict__ out) {
  if (blockIdx.x == T_TOK / 256) {
    const int lane = threadIdx.x;
    if (lane >= 64) return;
    float ms = 0.f;
    for (int b = 0; b < GEMM_B; ++b) ms += meb[(size_t)b * NE + lane];
    const float me = ms / (float)T_TOK;
    const float ce = (float)cnt1[lane] / (float)T_TOK;
    float v = me * ce;
#pragma unroll
    for (int o = 32; o; o >>= 1) v += __shfl_xor(v, o);
    if (lane == 0) out[0] = v * (float)NE;  // mean(me*ce)*E*E = sum*E
    return;
  }
  const int t = blockIdx.x * 256 + threadIdx.x;
  const int l1 = loc1[t], l2 = loc2[t];
  const bool k1 = l1 < CAP, k2 = l2 < CAP;
  const float a = k1 ? g1[t] : 0.f;
  const float b = k2 ? g2[t] : 0.f;
  const float denom = fmaxf(a + b, 1.1920929e-07f);  // finfo(f32).eps
  float* cw = out + 1;
  float* dm = out + 1 + (size_t)T_TOK * NE * CAP;
  if (k1) {
    size_t o = ((size_t)t * NE + idx1[t]) * CAP + l1;
    cw[o] = a / denom; dm[o] = 1.0f;
  }
  if (k2) {
    size_t o = ((size_t)t * NE + idx2[t]) * CAP + l2;
    cw[o] = b / denom; dm[o] = 1.0f;
  }
}

// ---------------------------------------------------------------- launcher
extern "C" void kernel_launch(void* const* d_in, const int* in_sizes, int n_in,
                              void* d_out, int out_size, void* d_ws, size_t ws_size,
                              hipStream_t stream) {
  const float* x   = (const float*)d_in[0];   // [8192, 2048]
  const float* wg  = (const float*)d_in[1];   // [64, 2048]
  const float* gum = (const float*)d_in[2];   // [8192, 64]
  float* out = (float*)d_out;

  // workspace layout (~230 KB)
  char* ws = (char*)d_ws;
  int*   idx1 = (int*)(ws + 0);
  int*   idx2 = (int*)(ws + 32768);
  float* g1   = (float*)(ws + 65536);
  float* g2   = (float*)(ws + 98304);
  int*   loc1 = (int*)(ws + 131072);
  int*   loc2 = (int*)(ws + 163840);
  int*   cnt1 = (int*)(ws + 196608);
  float* meb  = (float*)(ws + 196864);        // [128][64]

  const long n  = (long)out_size;             // 268,435,457 floats
  const long n4 = n >> 2;

  kA<<<dim3(GEMM_B + ZB), dim3(128), 0, stream>>>(
      x, wg, gum, idx1, idx2, g1, g2, meb, (float4*)out, n4, out, n);
  k_scan<<<dim3(NE), dim3(256), 0, stream>>>(idx1, idx2, loc1, loc2, cnt1);
  k_scat<<<dim3(T_TOK / 256 + 1), dim3(256), 0, stream>>>(
      idx1, idx2, g1, g2, loc1, loc2, meb, cnt1, out);
}